// Round 8
// baseline (1691.665 us; speedup 1.0000x reference)
//
#include <hip/hip_runtime.h>

#define Bb 64
#define Tt 2048
#define Ii 64
#define Hh 128
#define Gg 384   // 3*H
#define Oo 64

typedef _Float16 f16;
typedef _Float16 half8 __attribute__((ext_vector_type(8)));
typedef __fp16 fp16v2 __attribute__((ext_vector_type(2)));   // cvt_pkrtz native type
typedef float f32x4 __attribute__((ext_vector_type(4)));
typedef unsigned int u32;

static __device__ __forceinline__ float cvt_lo(u32 u) {
    fp16v2 v = __builtin_bit_cast(fp16v2, u);
    return (float)v[0];
}
static __device__ __forceinline__ float cvt_hi(u32 u) {
    fp16v2 v = __builtin_bit_cast(fp16v2, u);
    return (float)v[1];
}

// ---------------- K1: x-projection  xg[row,g] = dot(x[row,:], W_ih[g,:]) + b_ih[g]
// Layout: xR[row][j] = r-gate; xZN[row][2j] = z, xZN[row][2j+1] = n.
// Threads 128..383: lane-pairs (even,odd) = (z,n) for the same j -> packed b32 store.
__global__ __launch_bounds__(384, 2) void xproj_kernel(
    const float* __restrict__ inputs, const float* __restrict__ W_ih,
    const float* __restrict__ b_ih, f16* __restrict__ xR, f16* __restrict__ xZN,
    int rowsPerBlock)
{
    __shared__ __align__(16) float xs[16 * 64];
    const int tid = threadIdx.x;

    int wrow;
    if (tid < 128) wrow = tid;                       // r-gate row
    else {
        const int j = (tid - 128) >> 1;
        wrow = (tid & 1) ? (256 + j) : (128 + j);    // even->z, odd->n
    }

    float wi[64];
#pragma unroll
    for (int k = 0; k < 64; ++k) wi[k] = W_ih[(size_t)wrow * 64 + k];
#pragma unroll
    for (int k = 0; k < 64; ++k) asm volatile("" : "+v"(wi[k]));
    const float bi = b_ih[wrow];

    const int rowBase = blockIdx.x * rowsPerBlock;
    for (int c = 0; c < rowsPerBlock; c += 16) {
        __syncthreads();
        for (int idx = tid; idx < 16 * 64; idx += 384)
            xs[idx] = inputs[(size_t)(rowBase + c) * 64 + idx];
        __syncthreads();
#pragma unroll 4
        for (int rr = 0; rr < 16; ++rr) {
            const int row = rowBase + c + rr;
            const float4* x4 = (const float4*)&xs[rr * 64];
            float a0 = bi, a1 = 0.f, a2 = 0.f, a3 = 0.f;
#pragma unroll
            for (int i = 0; i < 16; ++i) {
                float4 v = x4[i];
                a0 = fmaf(v.x, wi[4 * i + 0], a0);
                a1 = fmaf(v.y, wi[4 * i + 1], a1);
                a2 = fmaf(v.z, wi[4 * i + 2], a2);
                a3 = fmaf(v.w, wi[4 * i + 3], a3);
            }
            const float acc = (a0 + a1) + (a2 + a3);
            if (tid < 128) {
                xR[(size_t)row * 128 + tid] = (f16)acc;
            } else {
                const float other = __shfl_xor(acc, 1);   // odd lane's n (on even)
                if (!(tid & 1)) {
                    const fp16v2 pk = __builtin_amdgcn_cvt_pkrtz(acc, other);
                    const int j = (tid - 128) >> 1;
                    *(u32*)(&xZN[(size_t)row * 256 + 2 * j]) =
                        __builtin_bit_cast(u32, pk);
                }
            }
        }
    }
}

// ---------------- K2: MFMA recurrence. 64 blocks x 512 threads; 1 batch/block.
// Per step: [1,128] @ W_hh^T via 16-row MFMA tile (rows 1-15 zero). Batch-0 C row
// lives in lanes hi=0, reg 0 -> those 16 lanes/wave eval gates directly.
// h' exchange: f16 h[128] in LDS (256 B), ping-pong, ONE RAW s_barrier/step:
// ds_write; s_waitcnt lgkmcnt(0); s_barrier  -- NO vmcnt drain (the __syncthreads
// vmcnt(0) drain was putting one HBM round-trip on every step's critical path).
// x-prefetch loads stay in flight across barriers, consumed 4 steps later.
__global__ __launch_bounds__(512, 2) void gru_mfma(
    const float* __restrict__ W_hh, const float* __restrict__ b_hh,
    const f16* __restrict__ xR, const f16* __restrict__ xZN,
    float* __restrict__ latents)
{
    __shared__ __align__(16) unsigned char hsm[2][256];   // h[128] f16, ping-pong

    const int tid = threadIdx.x;
    const int w   = tid >> 6;
    const int l   = tid & 63;
    const int lo  = l & 15;
    const int hi  = l >> 4;
    const int jj  = w * 16 + lo;      // this lane's hidden column
    const int bat = blockIdx.x;       // one batch per block

    // B fragments: lane lo -> col jj, hi -> k-chunk of 8; 8 consecutive k per reg.
    half8 Bf[3][4];
#pragma unroll
    for (int gt = 0; gt < 3; ++gt)
#pragma unroll
        for (int ks = 0; ks < 4; ++ks) {
            const float* wp = W_hh + (size_t)(gt * 128 + jj) * 128 + ks * 32 + hi * 8;
            half8 hv;
#pragma unroll
            for (int q = 0; q < 8; ++q) hv[q] = (f16)wp[q];
            Bf[gt][ks] = hv;
        }
#pragma unroll
    for (int gt = 0; gt < 3; ++gt)
#pragma unroll
        for (int ks = 0; ks < 4; ++ks)
            asm volatile("" : "+v"(Bf[gt][ks]));

    const float br = b_hh[jj];
    const float bz = b_hh[128 + jj];
    const float bn = b_hh[256 + jj];

    // Eval-lane streams (lanes l<16 own (bat, j=jj)).
    const f16* xrp  = xR  + (size_t)bat * Tt * 128 + jj;
    const f16* xznp = xZN + (size_t)bat * Tt * 256 + 2 * jj;
    float*     latp = latents + (size_t)bat * Tt * 128 + jj;

    // 4-deep x prefetch (slot s serves t%4 == s).
    f16 xrS[4];
    u32 xzS[4];
    if (l < 16) {
#pragma unroll
        for (int s = 0; s < 4; ++s) {
            xrS[s] = xrp[(size_t)s * 128];
            xzS[s] = *(const u32*)(xznp + (size_t)s * 256);
        }
    }

    float hreg = 0.f;
    half8 A[4];
    {
        half8 z8 = {};
#pragma unroll
        for (int ks = 0; ks < 4; ++ks) A[ks] = z8;   // rows 1-15 stay zero forever
    }

#define GSTEP(T, WP, IDX)                                                        \
    {                                                                            \
        const int t_ = (T);                                                      \
        float xr_ = 0.f, xz_ = 0.f, xn_ = 0.f;                                   \
        if (l < 16) {                                                            \
            xr_ = (float)xrS[IDX];                                               \
            xz_ = cvt_lo(xzS[IDX]);                                              \
            xn_ = cvt_hi(xzS[IDX]);                                              \
            if (t_ + 4 < Tt) {                                                   \
                xrS[IDX] = xrp[(size_t)(t_ + 4) * 128];                          \
                xzS[IDX] = *(const u32*)(xznp + (size_t)(t_ + 4) * 256);         \
            }                                                                    \
        }                                                                        \
        f32x4 accr = {br, br, br, br};                                           \
        f32x4 accz = {bz, bz, bz, bz};                                           \
        f32x4 accn = {bn, bn, bn, bn};                                           \
        _Pragma("unroll") for (int ks = 0; ks < 4; ++ks) {                       \
            accr = __builtin_amdgcn_mfma_f32_16x16x32_f16(A[ks], Bf[0][ks], accr, 0, 0, 0); \
            accz = __builtin_amdgcn_mfma_f32_16x16x32_f16(A[ks], Bf[1][ks], accz, 0, 0, 0); \
            accn = __builtin_amdgcn_mfma_f32_16x16x32_f16(A[ks], Bf[2][ks], accn, 0, 0, 0); \
        }                                                                        \
        if (l < 16) {                                                            \
            const float r = __builtin_amdgcn_rcpf(1.f + __expf(-(accr[0] + xr_))); \
            const float z = __builtin_amdgcn_rcpf(1.f + __expf(-(accz[0] + xz_))); \
            const float a = xn_ + r * accn[0];                                   \
            const float n = 1.f - 2.f * __builtin_amdgcn_rcpf(__expf(2.f * a) + 1.f); \
            const float hnew = n + z * (hreg - n);                               \
            hreg = hnew;                                                         \
            latp[(size_t)t_ * 128] = hnew;                                       \
            *(f16*)(&hsm[WP][2 * jj]) = (f16)hnew;                               \
        }                                                                        \
        /* LDS-only release: wait our ds ops, then raw barrier (no vmcnt drain) */ \
        asm volatile("s_waitcnt lgkmcnt(0)" ::: "memory");                       \
        __builtin_amdgcn_s_barrier();                                            \
        asm volatile("" ::: "memory");  /* no hoisting reads above barrier */    \
        if (lo == 0) {                                                           \
            _Pragma("unroll") for (int ks = 0; ks < 4; ++ks)                     \
                A[ks] = *(const half8*)(&hsm[WP][ks * 64 + hi * 16]);            \
        }                                                                        \
    }

    for (int t = 0; t < Tt; t += 4) {
        GSTEP(t,     0, 0)
        GSTEP(t + 1, 1, 1)
        GSTEP(t + 2, 0, 2)
        GSTEP(t + 3, 1, 3)
    }
#undef GSTEP
}

// ---------------- K3: out[row,o] = dot(latents[row,:], W_out[o,:]) + b_out[o]
__global__ __launch_bounds__(256, 1) void outproj_kernel(
    const float* __restrict__ latents, const float* __restrict__ W_out,
    const float* __restrict__ b_out, float* __restrict__ out, int rowsPerWave)
{
    const int lane = threadIdx.x & 63;
    const int wave = threadIdx.x >> 6;

    float w[128];
#pragma unroll
    for (int k = 0; k < 128; ++k) w[k] = W_out[(size_t)lane * 128 + k];
#pragma unroll
    for (int k = 0; k < 128; ++k) asm volatile("" : "+v"(w[k]));
    const float bo = b_out[lane];

    const int waveId  = blockIdx.x * 4 + wave;
    const int rowBase = waveId * rowsPerWave;

#pragma unroll 2
    for (int rr = 0; rr < rowsPerWave; ++rr) {
        const int row = rowBase + rr;
        const float4* l4 = (const float4*)(latents + (size_t)row * 128);
        float a0 = bo, a1 = 0.f, a2 = 0.f, a3 = 0.f;
#pragma unroll
        for (int i = 0; i < 32; ++i) {
            float4 v = l4[i];
            a0 = fmaf(v.x, w[4 * i + 0], a0);
            a1 = fmaf(v.y, w[4 * i + 1], a1);
            a2 = fmaf(v.z, w[4 * i + 2], a2);
            a3 = fmaf(v.w, w[4 * i + 3], a3);
        }
        out[(size_t)row * 64 + lane] = (a0 + a1) + (a2 + a3);
    }
}

extern "C" void kernel_launch(void* const* d_in, const int* in_sizes, int n_in,
                              void* d_out, int out_size, void* d_ws, size_t ws_size,
                              hipStream_t stream) {
    const float* inputs = (const float*)d_in[0];
    const float* W_ih   = (const float*)d_in[1];
    const float* W_hh   = (const float*)d_in[2];
    const float* b_ih   = (const float*)d_in[3];
    const float* b_hh   = (const float*)d_in[4];
    const float* W_out  = (const float*)d_in[5];
    const float* b_out  = (const float*)d_in[6];

    float* out     = (float*)d_out;
    float* latents = out + (size_t)Bb * Tt * Oo;

    // x_proj staging (f16): r-gates [B][T][128]; z/n interleaved [B][T][128][2].
    const size_t xbytes = (size_t)Bb * Tt * Gg * sizeof(f16);  // 100,663,296 B
    f16 *xR, *xZN;
    if (ws_size >= xbytes) {
        xR  = (f16*)d_ws;
        xZN = xR + (size_t)Bb * Tt * Hh;
    } else {
        // Alias into d_out: xR fits exactly in the output region, xZN exactly in
        // the latents region. K2's latents write at (b,t) lands on xZN row (b,t),
        // whose last read was the prefetch at step t-4; x reads at step t are
        // for row t+4. K3 overwrites the output region only after K2 completes.
        xR  = (f16*)d_out;
        xZN = (f16*)latents;
    }

    xproj_kernel<<<1024, 384, 0, stream>>>(inputs, W_ih, b_ih, xR, xZN,
                                           (Bb * Tt) / 1024);
    gru_mfma<<<Bb, 512, 0, stream>>>(W_hh, b_hh, xR, xZN, latents);
    outproj_kernel<<<2048, 256, 0, stream>>>(latents, W_out, b_out, out, 16);
}

// Round 9
// 1143.542 us; speedup vs baseline: 1.4793x; 1.4793x over previous
//
#include <hip/hip_runtime.h>

#define Bb 64
#define Tt 2048
#define Ii 64
#define Hh 128
#define Gg 384   // 3*H
#define Oo 64

typedef _Float16 f16;
typedef _Float16 half8 __attribute__((ext_vector_type(8)));
typedef __fp16 fp16v2 __attribute__((ext_vector_type(2)));   // cvt_pkrtz native type
typedef float f32x4 __attribute__((ext_vector_type(4)));
typedef unsigned int u32;

static __device__ __forceinline__ float cvt_lo(u32 u) {
    fp16v2 v = __builtin_bit_cast(fp16v2, u);
    return (float)v[0];
}
static __device__ __forceinline__ float cvt_hi(u32 u) {
    fp16v2 v = __builtin_bit_cast(fp16v2, u);
    return (float)v[1];
}

// ---------------- K1: x-projection  xg[row,g] = dot(x[row,:], W_ih[g,:]) + b_ih[g]
// Layout: xR[row][j] = r-gate; xZN[row][2j] = z, xZN[row][2j+1] = n.
__global__ __launch_bounds__(384, 2) void xproj_kernel(
    const float* __restrict__ inputs, const float* __restrict__ W_ih,
    const float* __restrict__ b_ih, f16* __restrict__ xR, f16* __restrict__ xZN,
    int rowsPerBlock)
{
    __shared__ __align__(16) float xs[16 * 64];
    const int tid = threadIdx.x;

    int wrow;
    if (tid < 128) wrow = tid;                       // r-gate row
    else {
        const int j = (tid - 128) >> 1;
        wrow = (tid & 1) ? (256 + j) : (128 + j);    // even->z, odd->n
    }

    float wi[64];
#pragma unroll
    for (int k = 0; k < 64; ++k) wi[k] = W_ih[(size_t)wrow * 64 + k];
#pragma unroll
    for (int k = 0; k < 64; ++k) asm volatile("" : "+v"(wi[k]));
    const float bi = b_ih[wrow];

    const int rowBase = blockIdx.x * rowsPerBlock;
    for (int c = 0; c < rowsPerBlock; c += 16) {
        __syncthreads();
        for (int idx = tid; idx < 16 * 64; idx += 384)
            xs[idx] = inputs[(size_t)(rowBase + c) * 64 + idx];
        __syncthreads();
#pragma unroll 4
        for (int rr = 0; rr < 16; ++rr) {
            const int row = rowBase + c + rr;
            const float4* x4 = (const float4*)&xs[rr * 64];
            float a0 = bi, a1 = 0.f, a2 = 0.f, a3 = 0.f;
#pragma unroll
            for (int i = 0; i < 16; ++i) {
                float4 v = x4[i];
                a0 = fmaf(v.x, wi[4 * i + 0], a0);
                a1 = fmaf(v.y, wi[4 * i + 1], a1);
                a2 = fmaf(v.z, wi[4 * i + 2], a2);
                a3 = fmaf(v.w, wi[4 * i + 3], a3);
            }
            const float acc = (a0 + a1) + (a2 + a3);
            if (tid < 128) {
                xR[(size_t)row * 128 + tid] = (f16)acc;
            } else {
                const float other = __shfl_xor(acc, 1);   // odd lane's n (on even)
                if (!(tid & 1)) {
                    const fp16v2 pk = __builtin_amdgcn_cvt_pkrtz(acc, other);
                    const int j = (tid - 128) >> 1;
                    *(u32*)(&xZN[(size_t)row * 256 + 2 * j]) =
                        __builtin_bit_cast(u32, pk);
                }
            }
        }
    }
}

// ---------------- K2: MFMA recurrence. 16 blocks x 512 threads; 4 batches/block.
// Batch b sits in A-row 4b (rows {0,4,8,12}; others zero). C/D: row = hi*4+reg,
// so row 4b => (hi=b, reg 0): lane (hi,lo) evals batch bb0+hi, col jj directly —
// NO redistribution (R6's 6 bpermutes+selects deleted). A-frag: row = lo, so
// lanes lo in {0,4,8,12} re-read h_b (4 x ds_read_b128); other lanes keep zero
// A regs forever. h store/load XORs bit6 by batch parity -> 2-way banks (free).
// h' exchange: ping-pong [2][1024]B, one __syncthreads per step (R6-validated).
__global__ __launch_bounds__(512, 2) void gru_mfma(
    const float* __restrict__ W_hh, const float* __restrict__ b_hh,
    const f16* __restrict__ xR, const f16* __restrict__ xZN,
    float* __restrict__ latents)
{
    __shared__ __align__(16) unsigned char hsm[2][1024];  // [b][j] f16, b-parity XOR

    const int tid = threadIdx.x;
    const int w   = tid >> 6;
    const int l   = tid & 63;
    const int lo  = l & 15;
    const int hi  = l >> 4;
    const int jj  = w * 16 + lo;      // this lane's hidden column
    const int bb0 = blockIdx.x * 4;   // 4 batches per block

    // B fragments: lane lo -> col jj, hi -> k-chunk of 8; 8 consecutive k per reg.
    half8 Bf[3][4];
#pragma unroll
    for (int gt = 0; gt < 3; ++gt)
#pragma unroll
        for (int ks = 0; ks < 4; ++ks) {
            const float* wp = W_hh + (size_t)(gt * 128 + jj) * 128 + ks * 32 + hi * 8;
            half8 hv;
#pragma unroll
            for (int q = 0; q < 8; ++q) hv[q] = (f16)wp[q];
            Bf[gt][ks] = hv;
        }
#pragma unroll
    for (int gt = 0; gt < 3; ++gt)
#pragma unroll
        for (int ks = 0; ks < 4; ++ks)
            asm volatile("" : "+v"(Bf[gt][ks]));

    const float br = b_hh[jj];
    const float bz = b_hh[128 + jj];
    const float bn = b_hh[256 + jj];

    // Per-lane streams: this lane owns (b = bb0 + hi, j = jj).
    const f16* xrp  = xR  + (size_t)(bb0 + hi) * Tt * 128 + jj;
    const f16* xznp = xZN + (size_t)(bb0 + hi) * Tt * 256 + 2 * jj;
    float*     latp = latents + (size_t)(bb0 + hi) * Tt * 128 + jj;

    // LDS addresses. Write (even-lo lanes, b32 j-pair): batch hi at hi*256,
    // byte (2*jj) ^ (parity<<6). Read (lanes lo=4b): b = lo>>2.
    const int waddr = hi * 256 + ((2 * jj) ^ ((hi & 1) << 6));
    const int rxor  = ((lo >> 2) & 1) << 6;
    const int rb    = (lo << 6);   // = (lo>>2)*256 for lo in {0,4,8,12}

    // 2-deep x prefetch: set A serves even t, set B serves odd t.
    f16 xrA = xrp[0];
    f16 xrB = xrp[128];
    u32 xzA = *(const u32*)xznp;
    u32 xzB = *(const u32*)(xznp + 256);

    float hreg = 0.f;
    half8 A[4];
    {
        half8 z8 = {};
#pragma unroll
        for (int ks = 0; ks < 4; ++ks) A[ks] = z8;   // rows != 4b stay zero forever
    }

#define GSTEP(T, WP, XRC, XZC)                                                   \
    {                                                                            \
        const int t_ = (T);                                                      \
        const float xr_ = (float)XRC;                                            \
        const float xz_ = cvt_lo(XZC);                                           \
        const float xn_ = cvt_hi(XZC);                                           \
        if (t_ + 2 < Tt) {                                                       \
            XRC = xrp[(size_t)(t_ + 2) * 128];                                   \
            XZC = *(const u32*)(xznp + (size_t)(t_ + 2) * 256);                  \
        }                                                                        \
        f32x4 accr = {br, br, br, br};                                           \
        f32x4 accz = {bz, bz, bz, bz};                                           \
        f32x4 accn = {bn, bn, bn, bn};                                           \
        _Pragma("unroll") for (int ks = 0; ks < 4; ++ks) {                       \
            accr = __builtin_amdgcn_mfma_f32_16x16x32_f16(A[ks], Bf[0][ks], accr, 0, 0, 0); \
            accz = __builtin_amdgcn_mfma_f32_16x16x32_f16(A[ks], Bf[1][ks], accz, 0, 0, 0); \
            accn = __builtin_amdgcn_mfma_f32_16x16x32_f16(A[ks], Bf[2][ks], accn, 0, 0, 0); \
        }                                                                        \
        /* batch bb0+hi row (=4*hi) lives in reg 0 of this lane group */         \
        const float r = __builtin_amdgcn_rcpf(1.f + __expf(-(accr[0] + xr_)));   \
        const float z = __builtin_amdgcn_rcpf(1.f + __expf(-(accz[0] + xz_)));   \
        const float a = xn_ + r * accn[0];                                       \
        const float n = 1.f - 2.f * __builtin_amdgcn_rcpf(__expf(2.f * a) + 1.f); \
        const float hnew = n + z * (hreg - n);                                   \
        hreg = hnew;                                                             \
        latp[(size_t)t_ * 128] = hnew;                                           \
        const float other = __shfl_xor(hnew, 1);                                 \
        if (!(l & 1)) {                                                          \
            const fp16v2 pkh = __builtin_amdgcn_cvt_pkrtz(hnew, other);          \
            *(fp16v2*)(&hsm[WP][waddr]) = pkh;                                   \
        }                                                                        \
        __syncthreads();                                                         \
        if (!(lo & 3)) {                                                         \
            _Pragma("unroll") for (int ks = 0; ks < 4; ++ks)                     \
                A[ks] = *(const half8*)(&hsm[WP][rb + ((ks * 64 + hi * 16) ^ rxor)]); \
        }                                                                        \
    }

    for (int t = 0; t < Tt; t += 2) {
        GSTEP(t,     0, xrA, xzA)
        GSTEP(t + 1, 1, xrB, xzB)
    }
#undef GSTEP
}

// ---------------- K3: out[row,o] = dot(latents[row,:], W_out[o,:]) + b_out[o]
__global__ __launch_bounds__(256, 1) void outproj_kernel(
    const float* __restrict__ latents, const float* __restrict__ W_out,
    const float* __restrict__ b_out, float* __restrict__ out, int rowsPerWave)
{
    const int lane = threadIdx.x & 63;
    const int wave = threadIdx.x >> 6;

    float w[128];
#pragma unroll
    for (int k = 0; k < 128; ++k) w[k] = W_out[(size_t)lane * 128 + k];
#pragma unroll
    for (int k = 0; k < 128; ++k) asm volatile("" : "+v"(w[k]));
    const float bo = b_out[lane];

    const int waveId  = blockIdx.x * 4 + wave;
    const int rowBase = waveId * rowsPerWave;

#pragma unroll 2
    for (int rr = 0; rr < rowsPerWave; ++rr) {
        const int row = rowBase + rr;
        const float4* l4 = (const float4*)(latents + (size_t)row * 128);
        float a0 = bo, a1 = 0.f, a2 = 0.f, a3 = 0.f;
#pragma unroll
        for (int i = 0; i < 32; ++i) {
            float4 v = l4[i];
            a0 = fmaf(v.x, w[4 * i + 0], a0);
            a1 = fmaf(v.y, w[4 * i + 1], a1);
            a2 = fmaf(v.z, w[4 * i + 2], a2);
            a3 = fmaf(v.w, w[4 * i + 3], a3);
        }
        out[(size_t)row * 64 + lane] = (a0 + a1) + (a2 + a3);
    }
}

extern "C" void kernel_launch(void* const* d_in, const int* in_sizes, int n_in,
                              void* d_out, int out_size, void* d_ws, size_t ws_size,
                              hipStream_t stream) {
    const float* inputs = (const float*)d_in[0];
    const float* W_ih   = (const float*)d_in[1];
    const float* W_hh   = (const float*)d_in[2];
    const float* b_ih   = (const float*)d_in[3];
    const float* b_hh   = (const float*)d_in[4];
    const float* W_out  = (const float*)d_in[5];
    const float* b_out  = (const float*)d_in[6];

    float* out     = (float*)d_out;
    float* latents = out + (size_t)Bb * Tt * Oo;

    // x_proj staging (f16): r-gates [B][T][128]; z/n interleaved [B][T][128][2].
    const size_t xbytes = (size_t)Bb * Tt * Gg * sizeof(f16);  // 100,663,296 B
    f16 *xR, *xZN;
    if (ws_size >= xbytes) {
        xR  = (f16*)d_ws;
        xZN = xR + (size_t)Bb * Tt * Hh;
    } else {
        // Alias into d_out: xR fits exactly in the output region, xZN exactly in
        // the latents region. K2's latents write at (b,t) lands on xZN row (b,t),
        // consumed two steps earlier (prefetch distance 2); x reads are always
        // for t+2. K3 overwrites the output region only after K2 completes.
        xR  = (f16*)d_out;
        xZN = (f16*)latents;
    }

    xproj_kernel<<<1024, 384, 0, stream>>>(inputs, W_ih, b_ih, xR, xZN,
                                           (Bb * Tt) / 1024);
    gru_mfma<<<16, 512, 0, stream>>>(W_hh, b_hh, xR, xZN, latents);
    outproj_kernel<<<2048, 256, 0, stream>>>(latents, W_out, b_out, out, 16);
}